// Round 6
// baseline (82.010 us; speedup 1.0000x reference)
//
#include <hip/hip_runtime.h>
#include <math.h>

// Problem constants (fixed by setup_inputs): bs=16, Q=300, C=2, P=320
#define BS 16
#define QN 300
#define CN 2
#define PN 320
#define NN (BS * QN)     // 4800 query rows
#define KPRED 53
#define KTGT 54

#define GRID 960         // persistent blocks
#define ROWS (NN / GRID) // 5 rows per block, exact
#define SROW 56          // staged row: 53 kpts + 2 logits, padded

// Persistent-block design: 960 blocks x 320 threads (thread <-> target p,
// 5 waves). Each block owns ROWS=5 query rows (n = bid + i*GRID).
// - Target features: loaded ONCE per block into registers (71 VGPRs),
//   amortized over 5 rows.
// - Pred rows: double-buffered 2x56-float LDS buffer, software-prefetched
//   one row ahead, ONE barrier per row. Steady-state inner loop touches no
//   global memory: broadcast ds_read (same addr all lanes = conflict-free)
//   + ~260 VALU + one fully-coalesced 320-lane store.
__global__ __launch_bounds__(PN) void hungarian_cost_kernel(
    const float* __restrict__ pred_logits,  // [N, 2]
    const float* __restrict__ pred_kpts,    // [N, 53]
    const float* __restrict__ tgt_kpts,     // [P, 54]
    const int*   __restrict__ tgt_ids,      // [P]
    float* __restrict__ out)                // [N, P]
{
    __shared__ float sk[2][SROW];
    const int p   = threadIdx.x;
    const int bid = blockIdx.x;

    // ---- per-thread target features, once per block ----
    float tx[18], ty[18], vjf[18], w[17];
    {
        const float* t = tgt_kpts + (size_t)p * KTGT;
        #pragma unroll
        for (int j = 0; j < 18; ++j) {
            tx[j] = t[3 * j];
            ty[j] = t[3 * j + 1];
            const float vv = t[3 * j + 2];
            vjf[j] = (vv == 1.0f) ? 1.0f : 0.0f;
            if (j >= 1) w[j - 1] = vv;   // tgt kpts-class vec aliases vis slots
        }
    }
    const int cls = tgt_ids[p];

    // ---- stage row 0 ----
    if (p < KPRED)          sk[0][p] = pred_kpts[(size_t)bid * KPRED + p];
    else if (p < KPRED + 2) sk[0][p] = pred_logits[(size_t)bid * CN + (p - KPRED)];
    __syncthreads();

    #pragma unroll
    for (int i = 0; i < ROWS; ++i) {
        const int n   = bid + i * GRID;
        const int cur = i & 1;

        // prefetch row i+1 into the other buffer (overlaps compute below)
        {
            const int nn_ = (i + 1 < ROWS) ? (n + GRID) : n;  // harmless restage on last
            if (p < KPRED)          sk[cur ^ 1][p] = pred_kpts[(size_t)nn_ * KPRED + p];
            else if (p < KPRED + 2) sk[cur ^ 1][p] = pred_logits[(size_t)nn_ * CN + (p - KPRED)];
        }

        const float* k = sk[cur];   // broadcast LDS reads

        const float dx0 = k[0] - tx[0];
        const float dy0 = k[1] - ty[0];

        float cd = 0.0f;   // cost_deltas (L1, relative coords)
        float ck = 0.0f;   // cost_kpts:  xa - txa = 2*dx + dx0
        float cq = 0.0f;   // kpts-class squared L2
        #pragma unroll
        for (int j = 1; j < 18; ++j) {
            const float dx = k[3 * j - 1] - tx[j];
            const float dy = k[3 * j]     - ty[j];
            cd = fmaf(vjf[j], fabsf(dx) + fabsf(dy), cd);
            const float ax = fmaf(2.0f, dx, dx0);
            const float ay = fmaf(2.0f, dy, dy0);
            ck = fmaf(vjf[j], fabsf(ax) + fabsf(ay), ck);
            const float d = k[3 * j + 1] - w[j - 1];
            cq = fmaf(d, d, cq);
        }

        // cost_ctrs = vis0 * ||(dx0, dy0)||
        const float cc = vjf[0] * sqrtf(fmaf(dx0, dx0, dy0 * dy0));

        // cost_class = -softmax(logits)[cls]
        const float l0 = k[KPRED], l1 = k[KPRED + 1];
        const float m  = fmaxf(l0, l1);
        const float e0 = __expf(l0 - m);
        const float e1 = __expf(l1 - m);
        const float ccls = -((cls == 0) ? e0 : e1) / (e0 + e1);

        out[(size_t)n * PN + p] = ck + cc + cd + ccls + sqrtf(cq);

        __syncthreads();   // joins prefetch-writes and compute-reads
    }
}

extern "C" void kernel_launch(void* const* d_in, const int* in_sizes, int n_in,
                              void* d_out, int out_size, void* d_ws, size_t ws_size,
                              hipStream_t stream) {
    const float* pred_logits = (const float*)d_in[0];
    const float* pred_kpts   = (const float*)d_in[1];
    const float* tgt_kpts    = (const float*)d_in[2];
    const int*   tgt_ids     = (const int*)d_in[3];
    float* out = (float*)d_out;

    hipLaunchKernelGGL(hungarian_cost_kernel, dim3(GRID), dim3(PN), 0, stream,
                       pred_logits, pred_kpts, tgt_kpts, tgt_ids, out);
}